// Round 7
// baseline (227.455 us; speedup 1.0000x reference)
//
#include <hip/hip_runtime.h>
#include <cmath>

typedef __attribute__((ext_vector_type(8))) short short8;
typedef __attribute__((ext_vector_type(4))) short short4v;
typedef __attribute__((ext_vector_type(16))) float floatx16;
typedef unsigned short ushort_t;

#define LSEQ   2048
#define DMODEL 1024
#define BM 128
#define BN 128
#define BK 64
#define BN2 256    // qkv col-tile
#define TPAD 136   // transpose LDS row stride (elems)

// log2(0.96875)
#define L2GAMMA (-0.045803595f)
// log2(10000)/512
#define L2E4_512 (0.0259525632f)

__device__ __forceinline__ ushort_t f2b(float x) {
    union { float f; unsigned u; } v; v.f = x;
    unsigned r = v.u + 0x7fffu + ((v.u >> 16) & 1u);
    return (ushort_t)(r >> 16);
}

#define GLOAD_LDS16(gptr, lptr)                                                     \
    __builtin_amdgcn_global_load_lds(                                               \
        (const __attribute__((address_space(1))) unsigned int*)(gptr),              \
        (__attribute__((address_space(3))) unsigned int*)(lptr), 16, 0, 0)

// ---------------------------------------------------------------------------
// 256-thread GEMM core (score/av): C(128x128) += A * B^T, 32x32x16 bf16,
// BK=64, XOR-swizzled 16-B chunks.
// ---------------------------------------------------------------------------
__device__ __forceinline__ void gemm_core(
    const ushort_t* __restrict__ Ag, int lda, int aRow0,
    const ushort_t* __restrict__ Bg, int ldb, int bRow0,
    int kDepth, ushort_t* As, ushort_t* Bs, floatx16 acc[2][2])
{
    const int tid  = threadIdx.x;
    const int wave = tid >> 6, lane = tid & 63;
    const int wm = wave >> 1, wn = wave & 1;
    const int l31 = lane & 31, half = lane >> 5;
    const int srow = lane >> 3;
    const int scol = ((lane & 7) ^ srow) * 8;

    const ushort_t* ap[4];
    const ushort_t* bp[4];
    #pragma unroll
    for (int L = 0; L < 4; ++L) {
        int r = (wave * 4 + L) * 8 + srow;
        ap[L] = Ag + (size_t)(aRow0 + r) * lda + scol;
        bp[L] = Bg + (size_t)(bRow0 + r) * ldb + scol;
    }
    const int ldst = srow * BK + (lane & 7) * 8;

    for (int k0 = 0; k0 < kDepth; k0 += BK) {
        __syncthreads();
        #pragma unroll
        for (int L = 0; L < 4; ++L) {
            GLOAD_LDS16(ap[L], As + (wave * 4 + L) * (8 * BK) + ldst);
            GLOAD_LDS16(bp[L], Bs + (wave * 4 + L) * (8 * BK) + ldst);
            ap[L] += BK; bp[L] += BK;
        }
        __syncthreads();

        #pragma unroll
        for (int ks = 0; ks < 4; ++ks) {
            const int ch = ((ks * 2 + half) ^ (l31 & 7)) * 8;
            short8 a0 = *(const short8*)(As + (wm * 64      + l31) * BK + ch);
            short8 a1 = *(const short8*)(As + (wm * 64 + 32 + l31) * BK + ch);
            short8 b0 = *(const short8*)(Bs + (wn * 64      + l31) * BK + ch);
            short8 b1 = *(const short8*)(Bs + (wn * 64 + 32 + l31) * BK + ch);
            acc[0][0] = __builtin_amdgcn_mfma_f32_32x32x16_bf16(a0, b0, acc[0][0], 0, 0, 0);
            acc[0][1] = __builtin_amdgcn_mfma_f32_32x32x16_bf16(a0, b1, acc[0][1], 0, 0, 0);
            acc[1][0] = __builtin_amdgcn_mfma_f32_32x32x16_bf16(a1, b0, acc[1][0], 0, 0, 0);
            acc[1][1] = __builtin_amdgcn_mfma_f32_32x32x16_bf16(a1, b1, acc[1][1], 0, 0, 0);
        }
    }
}
// C/D layout 32x32x16: col = lane&31 (+ni*32), row = (reg&3) + 8*(reg>>2) +
// 4*(lane>>5) (+mi*32); reg = rg*4+q -> 4 consecutive rows per rg group.

// ---------------------------------------------------------------------------
// 512-thread GEMM core (qkv): C(128x256) += A(128xK) * B(256xK)^T.
// 8 waves in 2x4 grid; each wave 64x64 (2x2 of 32x32) -> same 64-AGPR
// budget as the 256-thread core (no register cliff).
// ---------------------------------------------------------------------------
__device__ __forceinline__ void gemm_core512(
    const ushort_t* __restrict__ Ag, int lda, int aRow0,
    const ushort_t* __restrict__ Bg, int ldb, int bRow0,
    int kDepth, ushort_t* As, ushort_t* Bs, floatx16 acc[2][2])
{
    const int tid  = threadIdx.x;
    const int w = tid >> 6, lane = tid & 63;
    const int wm = w >> 2, wn = w & 3;
    const int l31 = lane & 31, half = lane >> 5;
    const int srow = lane >> 3;
    const int scol = ((lane & 7) ^ srow) * 8;

    const ushort_t* ap[2];
    const ushort_t* bp[4];
    #pragma unroll
    for (int L = 0; L < 2; ++L)
        ap[L] = Ag + (size_t)(aRow0 + (w + L * 8) * 8 + srow) * lda + scol;
    #pragma unroll
    for (int L = 0; L < 4; ++L)
        bp[L] = Bg + (size_t)(bRow0 + (w + L * 8) * 8 + srow) * ldb + scol;
    const int ldst = srow * BK + (lane & 7) * 8;

    for (int k0 = 0; k0 < kDepth; k0 += BK) {
        __syncthreads();
        #pragma unroll
        for (int L = 0; L < 2; ++L) {
            GLOAD_LDS16(ap[L], As + (w + L * 8) * (8 * BK) + ldst);
            ap[L] += BK;
        }
        #pragma unroll
        for (int L = 0; L < 4; ++L) {
            GLOAD_LDS16(bp[L], Bs + (w + L * 8) * (8 * BK) + ldst);
            bp[L] += BK;
        }
        __syncthreads();

        #pragma unroll
        for (int ks = 0; ks < 4; ++ks) {
            const int ch = ((ks * 2 + half) ^ (l31 & 7)) * 8;
            short8 a0 = *(const short8*)(As + (wm * 64      + l31) * BK + ch);
            short8 a1 = *(const short8*)(As + (wm * 64 + 32 + l31) * BK + ch);
            short8 b0 = *(const short8*)(Bs + (wn * 64      + l31) * BK + ch);
            short8 b1 = *(const short8*)(Bs + (wn * 64 + 32 + l31) * BK + ch);
            acc[0][0] = __builtin_amdgcn_mfma_f32_32x32x16_bf16(a0, b0, acc[0][0], 0, 0, 0);
            acc[0][1] = __builtin_amdgcn_mfma_f32_32x32x16_bf16(a0, b1, acc[0][1], 0, 0, 0);
            acc[1][0] = __builtin_amdgcn_mfma_f32_32x32x16_bf16(a1, b0, acc[1][0], 0, 0, 0);
            acc[1][1] = __builtin_amdgcn_mfma_f32_32x32x16_bf16(a1, b1, acc[1][1], 0, 0, 0);
        }
    }
}

// ---------------------------------------------------------------------------
// Prep: xpos (cos,sin) tables with xpos-scale AND decay gamma^{+-l} folded in.
// ---------------------------------------------------------------------------
__global__ __launch_bounds__(256) void xpos_table_kernel(float2* __restrict__ T)
{
    int idx = blockIdx.x * 256 + threadIdx.x;   // 2*512*2048 entries
    int l = idx & 2047;
    int p = (idx >> 11) & 511;
    int mode = idx >> 20;
    float sv = (2.0f * (float)p + 409.6f) * (1.0f / 1433.6f);
    float coeff = log2f(sv) * (1.0f / 512.0f) + L2GAMMA;
    float invf = exp2f(-(float)p * L2E4_512);
    float lf = (float)l;
    float s, c;
    sincosf(lf * invf, &s, &c);
    float g = exp2f((mode == 0 ? lf : -lf) * coeff);
    T[idx] = make_float2(c * g, s * g);
}

// ---------------------------------------------------------------------------
// Prep: fp32 -> bf16 cast of X
// ---------------------------------------------------------------------------
__global__ __launch_bounds__(256) void cast_x_kernel(
    const float4* __restrict__ X, short4v* __restrict__ Xb, int n4)
{
    int i = blockIdx.x * 256 + threadIdx.x;
    if (i < n4) {
        float4 v = X[i];
        short4v o;
        o.x = (short)f2b(v.x); o.y = (short)f2b(v.y);
        o.z = (short)f2b(v.z); o.w = (short)f2b(v.w);
        Xb[i] = o;
    }
}

// ---------------------------------------------------------------------------
// Prep: W (fp32 [K][N]) -> Wt (bf16 [N][K]) for all three weights
// ---------------------------------------------------------------------------
__global__ __launch_bounds__(256) void wtrans_kernel(
    const float* __restrict__ Wq, const float* __restrict__ Wk,
    const float* __restrict__ Wv, ushort_t* __restrict__ Wt)
{
    const float* W = blockIdx.z == 0 ? Wq : blockIdx.z == 1 ? Wk : Wv;
    ushort_t* O = Wt + (size_t)blockIdx.z * (DMODEL * DMODEL);
    __shared__ float t[32][33];
    const int x = threadIdx.x & 31, y = (threadIdx.x >> 5) * 4;
    const int k0 = blockIdx.y * 32, n0 = blockIdx.x * 32;
    #pragma unroll
    for (int j = 0; j < 4; ++j)
        t[y + j][x] = W[(size_t)(k0 + y + j) * DMODEL + n0 + x];
    __syncthreads();
    #pragma unroll
    for (int j = 0; j < 4; ++j)
        O[(size_t)(n0 + y + j) * DMODEL + k0 + x] = f2b(t[x][y + j]);
}

// ---------------------------------------------------------------------------
// Stage 1: Q/K/V = Xb @ W, 128x256 tiles, 512 threads. 12 col-tiles over
// [Wq|Wk|Wv]: mode = ct>>2 (no mode mixing in a block). V epilogue: LDS
// transpose in two 128-col halves (reuses the 48 KB staging LDS).
// ---------------------------------------------------------------------------
__global__ __launch_bounds__(512, 4) void qkv_kernel(
    const ushort_t* __restrict__ Xb, const ushort_t* __restrict__ Wt,
    const float2* __restrict__ Tab,
    ushort_t* __restrict__ Q, ushort_t* __restrict__ Ko, ushort_t* __restrict__ Vt)
{
    __shared__ ushort_t smem[(BM + BN2) * BK];   // 48 KB
    ushort_t* As = smem;
    ushort_t* Bs = smem + BM * BK;

    const int ct = blockIdx.x;             // 0..11
    const int mode = ct >> 2;
    const int c0 = (ct & 3) * BN2;         // col within mode, 0..768
    const int row0 = blockIdx.y * BM;

    floatx16 acc[2][2] = {};
    gemm_core512(Xb, DMODEL, row0,
                 Wt + (size_t)mode * (DMODEL * DMODEL), DMODEL, c0,
                 DMODEL, As, Bs, acc);

    const int w = threadIdx.x >> 6, lane = threadIdx.x & 63;
    const int wm = w >> 2, wn = w & 3;
    const int l31 = lane & 31, half = lane >> 5;
    const int rBase = row0 + wm * 64 + 4 * half;   // + mi*32 + 8*rg + q
    const int cBase = c0 + wn * 64 + l31;          // + ni*32

    if (mode == 2) {
        const int b = row0 >> 11, lpos0 = row0 & 2047;
        const int t = threadIdx.x;
        #pragma unroll
        for (int h = 0; h < 2; ++h) {
            __syncthreads();   // staging (h=0) / previous half's reads done
            if ((wn >> 1) == h) {
                const int colL0 = (wn & 1) * 64 + l31;   // 0..127 within half
                #pragma unroll
                for (int ni = 0; ni < 2; ++ni)
                    #pragma unroll
                    for (int mi = 0; mi < 2; ++mi)
                        #pragma unroll
                        for (int rg = 0; rg < 4; ++rg) {
                            short4v pk;
                            pk.x = (short)f2b(acc[mi][ni][rg * 4 + 0]);
                            pk.y = (short)f2b(acc[mi][ni][rg * 4 + 1]);
                            pk.z = (short)f2b(acc[mi][ni][rg * 4 + 2]);
                            pk.w = (short)f2b(acc[mi][ni][rg * 4 + 3]);
                            *(short4v*)(smem + (colL0 + ni * 32) * TPAD
                                             + wm * 64 + 4 * half
                                             + mi * 32 + 8 * rg) = pk;
                        }
            }
            __syncthreads();
            // store half h: thread t -> col = t>>2, 32-row strip (t&3)
            const int colV = c0 + h * 128 + (t >> 2);
            const int r0 = (t & 3) * 32;
            #pragma unroll
            for (int i = 0; i < 4; ++i) {
                short8 vv = *(const short8*)(smem + (t >> 2) * TPAD + r0 + i * 8);
                *(short8*)(Vt + (size_t)b * (LSEQ * DMODEL)
                              + (size_t)colV * LSEQ + lpos0 + r0 + i * 8) = vv;
            }
        }
    } else {
        ushort_t* O = (mode == 0) ? Q : Ko;
        const float2* Tm = Tab + (size_t)mode * (512 * 2048);
        #pragma unroll
        for (int ni = 0; ni < 2; ++ni) {
            int col = cBase + ni * 32;
            const float2* tp = Tm + ((size_t)(col >> 1) << 11);
            #pragma unroll
            for (int mi = 0; mi < 2; ++mi)
                #pragma unroll
                for (int rg = 0; rg < 4; ++rg) {
                    int l0 = (rBase + mi * 32 + 8 * rg) & 2047;
                    float4 t01 = *(const float4*)(tp + l0);
                    float4 t23 = *(const float4*)(tp + l0 + 2);
                    float cs[8] = {t01.x, t01.y, t01.z, t01.w,
                                   t23.x, t23.y, t23.z, t23.w};
                    #pragma unroll
                    for (int q = 0; q < 4; ++q) {
                        int row = rBase + mi * 32 + 8 * rg + q;
                        float cc = cs[2 * q], ss = cs[2 * q + 1];
                        float v  = acc[mi][ni][rg * 4 + q];
                        float pv = __shfl_xor(v, 1);
                        float res = (lane & 1) ? fmaf(v, cc, pv * ss)
                                               : fmaf(v, cc, -pv * ss);
                        O[(size_t)row * DMODEL + col] = f2b(res);
                    }
                }
        }
    }
}

// ---------------------------------------------------------------------------
// Stage 2: S = Q-hat . K-hat^T (decay pre-folded), banded (bi-2..bi),
// mask upper triangle. 45 tiles per batch.
// ---------------------------------------------------------------------------
__global__ __launch_bounds__(256, 4) void score_kernel(
    const ushort_t* __restrict__ Q, const ushort_t* __restrict__ Kc,
    ushort_t* __restrict__ S)
{
    const int t = blockIdx.x, z = blockIdx.z;
    int bi, bj;
    if (t < 3) { bi = (t > 0); bj = t - (t > 0); }
    else { int u = t - 3; bi = 2 + u / 3; bj = bi - 2 + u % 3; }

    __shared__ ushort_t As[BM * BK], Bs[BN * BK];
    floatx16 acc[2][2] = {};
    const size_t zoff = (size_t)z * (LSEQ * DMODEL);
    gemm_core(Q + zoff, DMODEL, bi * BM, Kc + zoff, DMODEL, bj * BN,
              DMODEL, As, Bs, acc);

    const int wave = threadIdx.x >> 6, lane = threadIdx.x & 63;
    const int wm = wave >> 1, wn = wave & 1;
    const int l31 = lane & 31, half = lane >> 5;
    const int nBase = bi * BM + wm * 64 + 4 * half;
    const int mBase = bj * BN + wn * 64 + l31;
    ushort_t* Sz = S + (size_t)z * LSEQ * LSEQ;
    #pragma unroll
    for (int mi = 0; mi < 2; ++mi)
        #pragma unroll
        for (int ni = 0; ni < 2; ++ni) {
            int m = mBase + ni * 32;
            #pragma unroll
            for (int rg = 0; rg < 4; ++rg)
                #pragma unroll
                for (int q = 0; q < 4; ++q) {
                    int n = nBase + mi * 32 + 8 * rg + q;
                    Sz[(size_t)n * LSEQ + m] =
                        (m <= n) ? f2b(acc[mi][ni][rg * 4 + q]) : (ushort_t)0;
                }
        }
}

// ---------------------------------------------------------------------------
// Stage 3: O = S @ V, banded k-window [max(0,(bi-2)*128), (bi+1)*128).
// ---------------------------------------------------------------------------
__global__ __launch_bounds__(256, 4) void av_kernel(
    const ushort_t* __restrict__ S, const ushort_t* __restrict__ Vt,
    float* __restrict__ Out)
{
    const int bx = blockIdx.x, bi = blockIdx.y, z = blockIdx.z;
    const int kLo = (bi >= 2) ? (bi - 2) * BM : 0;
    const int kW  = (bi + 1) * BM - kLo;
    __shared__ ushort_t As[BM * BK], Bs[BN * BK];
    floatx16 acc[2][2] = {};
    gemm_core(S + (size_t)z * LSEQ * LSEQ + kLo, LSEQ, bi * BM,
              Vt + (size_t)z * (LSEQ * DMODEL) + kLo, LSEQ, bx * BN,
              kW, As, Bs, acc);

    const int wave = threadIdx.x >> 6, lane = threadIdx.x & 63;
    const int wm = wave >> 1, wn = wave & 1;
    const int l31 = lane & 31, half = lane >> 5;
    const int rBase = bi * BM + wm * 64 + 4 * half;
    const int cBase = bx * BN + wn * 64 + l31;
    float* Oz = Out + (size_t)z * (LSEQ * DMODEL);
    #pragma unroll
    for (int mi = 0; mi < 2; ++mi)
        #pragma unroll
        for (int ni = 0; ni < 2; ++ni)
            #pragma unroll
            for (int rg = 0; rg < 4; ++rg)
                #pragma unroll
                for (int q = 0; q < 4; ++q)
                    Oz[(size_t)(rBase + mi * 32 + 8 * rg + q) * DMODEL
                       + cBase + ni * 32] = acc[mi][ni][rg * 4 + q];
}

// ---------------------------------------------------------------------------
extern "C" void kernel_launch(void* const* d_in, const int* in_sizes, int n_in,
                              void* d_out, int out_size, void* d_ws, size_t ws_size,
                              hipStream_t stream)
{
    const float* X  = (const float*)d_in[0];
    const float* Wq = (const float*)d_in[1];
    const float* Wk = (const float*)d_in[2];
    const float* Wv = (const float*)d_in[3];
    float* out = (float*)d_out;

    const size_t LH  = (size_t)LSEQ * DMODEL;
    const size_t WSZ = (size_t)DMODEL * DMODEL;
    const size_t SSZ = (size_t)LSEQ * LSEQ;
    const size_t TABN = (size_t)2 * 512 * 2048;

    size_t need4 = TABN * 8 + 2 * (3 * WSZ + 4 * (4 * LH + SSZ));  // ~124 MB
    const int bs = (ws_size >= need4) ? 4 : 1;

    float2* Tab = (float2*)d_ws;
    ushort_t* ws16 = (ushort_t*)(Tab + TABN);
    ushort_t* Wt = ws16;
    ushort_t* Xb = Wt + 3 * WSZ;
    ushort_t* Q  = Xb + (size_t)bs * LH;
    ushort_t* Kb = Q  + (size_t)bs * LH;
    ushort_t* Vt = Kb + (size_t)bs * LH;
    ushort_t* S  = Vt + (size_t)bs * LH;

    xpos_table_kernel<<<dim3(TABN / 256), 256, 0, stream>>>(Tab);
    wtrans_kernel<<<dim3(32, 32, 3), 256, 0, stream>>>(Wq, Wk, Wv, Wt);

    for (int p = 0; p < 4 / bs; ++p) {
        const float* Xp = X + (size_t)p * bs * LH;
        cast_x_kernel<<<dim3(bs * 2048), 256, 0, stream>>>(
            (const float4*)Xp, (short4v*)Xb, bs * (int)(LH / 4));
        qkv_kernel<<<dim3(12, bs * 16), 512, 0, stream>>>(
            Xb, Wt, Tab, Q, Kb, Vt);
        score_kernel<<<dim3(45, 1, bs), 256, 0, stream>>>(Q, Kb, S);
        av_kernel<<<dim3(8, 16, bs), 256, 0, stream>>>(S, Vt,
            out + (size_t)p * bs * LH);
    }
}